// Round 3
// baseline (40486.890 us; speedup 1.0000x reference)
//
#include <hip/hip_runtime.h>

// Problem constants (fixed by the reference)
#define BATCH 2048
#define TT    256
#define DD    128
#define HH    256
#define PP    2048
#define RR    8     // batch rows per block (2048 rows / 256 CUs)
#define NTH   512   // 8 waves/CU = 2 waves/SIMD

__device__ __forceinline__ float sigmoidf_(float v) { return 1.0f / (1.0f + expf(-v)); }

// Streaming-friendly weight layouts:
//   wIH2[k*768 + g*256 + j] = w_ih[g*256+j][k]   (k<128)
//   wHH2[k*768 + g*256 + j] = w_hh[g*256+j][k]   (k<256)
//   pT[k*2048 + p]          = protos[p][k]
__global__ void prep_kernel(const float* __restrict__ w_ih, const float* __restrict__ w_hh,
                            const float* __restrict__ protos,
                            float* __restrict__ wIH2, float* __restrict__ wHH2,
                            float* __restrict__ pT) {
    int f = blockIdx.x * blockDim.x + threadIdx.x;
    if (f < DD * 768) {
        int k = f / 768, rem = f - k * 768, g = rem >> 8, j = rem & 255;
        wIH2[f] = w_ih[(g * 256 + j) * DD + k];
    }
    if (f < HH * 768) {
        int k = f / 768, rem = f - k * 768, g = rem >> 8, j = rem & 255;
        wHH2[f] = w_hh[(g * 256 + j) * HH + k];
    }
    if (f < HH * PP) {
        pT[f] = protos[(f & 2047) * HH + (f >> 11)];
    }
}

// part[s][r][kh][j]: s in {r,z,xn,hn}, r row, kh k-half, j unit
#define PARTI(s, r, h, j) ((((s) * 8 + (r)) * 2 + (h)) * 256 + (j))

// Load one 8-k weight block (24 floats) into a register buffer.
#define LOADIH(buf, k0) do {                                                   \
    _Pragma("unroll")                                                          \
    for (int u = 0; u < 8; ++u) {                                              \
        (buf)[3*u+0] = ihq[((k0) + u) * 768 + 0];                              \
        (buf)[3*u+1] = ihq[((k0) + u) * 768 + 256];                            \
        (buf)[3*u+2] = ihq[((k0) + u) * 768 + 512];                            \
    } } while (0)
#define LOADHH(buf, k0) do {                                                   \
    _Pragma("unroll")                                                          \
    for (int u = 0; u < 8; ++u) {                                              \
        (buf)[3*u+0] = hhq[((k0) + u) * 768 + 0];                              \
        (buf)[3*u+1] = hhq[((k0) + u) * 768 + 256];                            \
        (buf)[3*u+2] = hhq[((k0) + u) * 768 + 512];                            \
    } } while (0)
// FMA one 8-k block against activations (LDS broadcast reads), 8 rows.
#define FMABLK(buf, act, k0, pn) do {                                          \
    _Pragma("unroll")                                                          \
    for (int u = 0; u < 8; ++u) {                                              \
        const float w_r = (buf)[3*u+0], w_z = (buf)[3*u+1], w_n = (buf)[3*u+2];\
        const float4 v0 = *(const float4*)((act) + ((k0) + u) * 8);            \
        const float4 v1 = *(const float4*)((act) + ((k0) + u) * 8 + 4);        \
        const float vv[8] = {v0.x, v0.y, v0.z, v0.w, v1.x, v1.y, v1.z, v1.w};  \
        _Pragma("unroll")                                                      \
        for (int r = 0; r < 8; ++r) {                                          \
            pr[r] += vv[r] * w_r; pz[r] += vv[r] * w_z; pn[r] += vv[r] * w_n;  \
        }                                                                      \
    } } while (0)

__launch_bounds__(NTH, 2)
__global__ void gru_kernel(const float* __restrict__ x,
                           const float* __restrict__ wIH2, const float* __restrict__ wHH2,
                           const float* __restrict__ b_ih, const float* __restrict__ b_hh,
                           const float* __restrict__ pT,
                           int* __restrict__ out) {
    __shared__ float xs[2][DD][RR];          // 8 KB  x_t staging (k-major), double-buffered
    __shared__ float hs[HH][RR];             // 8 KB  hidden state (k-major)
    __shared__ float part[4 * 8 * 2 * 256];  // 64 KB partial sums
    __shared__ float redv[8][RR];
    __shared__ int   redi[8][RR];

    const int tid = threadIdx.x;
    const int j   = tid & 255;     // hidden unit
    const int kh  = tid >> 8;      // k-half (0/1)
    const int row0 = blockIdx.x * RR;

    const float bR  = b_ih[j] + b_hh[j];
    const float bZ  = b_ih[HH + j] + b_hh[HH + j];
    const float bXN = b_ih[2 * HH + j];
    const float bHN = b_hh[2 * HH + j];

    float hcur[4] = {0.f, 0.f, 0.f, 0.f};   // rows 4*kh .. 4*kh+3 of unit j
    *(float4*)&hs[j][4 * kh] = make_float4(0.f, 0.f, 0.f, 0.f);

    // x loader mapping (first 4 waves): row lr, 4 cols at lk
    const int lr = tid >> 5;
    const int lk = (tid & 31) * 4;
    const float* xrow = x + (size_t)(row0 + lr) * TT * DD + lk;
    if (tid < 256) {
        float4 v = *(const float4*)(xrow);
        xs[0][lk + 0][lr] = v.x; xs[0][lk + 1][lr] = v.y;
        xs[0][lk + 2][lr] = v.z; xs[0][lk + 3][lr] = v.w;
    }
    __syncthreads();

    // per-thread weight stream bases (absolute k range: ih [64*kh,64*kh+64), hh [128*kh,+128))
    const float* ihq = wIH2 + (size_t)(64 * kh) * 768 + j;
    const float* hhq = wHH2 + (size_t)(128 * kh) * 768 + j;
    const float* hb  = &hs[128 * kh][0];

    for (int t = 0; t < TT; ++t) {
        const int cur = t & 1, nxt = cur ^ 1;
        const float* xb = &xs[cur][64 * kh][0];

        float4 pf;
        const bool havepf = (t + 1 < TT) && (tid < 256);
        if (havepf) pf = *(const float4*)(xrow + (size_t)(t + 1) * DD);

        float pr[8], pz[8], pxn[8], phn[8];
        #pragma unroll
        for (int r = 0; r < 8; ++r) { pr[r] = 0.f; pz[r] = 0.f; pxn[r] = 0.f; phn[r] = 0.f; }

        // prime the pipeline: 2 ih blocks + 2 hh blocks in flight
        float wa[24], wb[24], wc[24], wd[24];
        LOADIH(wa, 0); LOADIH(wb, 8);
        LOADHH(wc, 0); LOADHH(wd, 8);

        // ---- input projection (64 k per thread, 2 blocks per iter) ----
        for (int kb = 0; kb < 4; ++kb) {
            const int k0 = kb * 16;
            FMABLK(wa, xb, k0, pxn);
            if (kb < 3) LOADIH(wa, k0 + 16);
            FMABLK(wb, xb, k0 + 8, pxn);
            if (kb < 3) LOADIH(wb, k0 + 24);
        }
        // ---- hidden projection (128 k per thread) ----
        for (int kb = 0; kb < 8; ++kb) {
            const int k0 = kb * 16;
            FMABLK(wc, hb, k0, phn);
            if (kb < 7) LOADHH(wc, k0 + 16);
            FMABLK(wd, hb, k0 + 8, phn);
            if (kb < 7) LOADHH(wd, k0 + 24);
        }

        // ---- publish partials (consecutive-j: conflict-free) ----
        #pragma unroll
        for (int r = 0; r < 8; ++r) {
            part[PARTI(0, r, kh, j)] = pr[r];
            part[PARTI(1, r, kh, j)] = pz[r];
            part[PARTI(2, r, kh, j)] = pxn[r];
            part[PARTI(3, r, kh, j)] = phn[r];
        }
        __syncthreads();   // A: partials visible; all xs/hs reads done

        // ---- gates for rows 4*kh..4*kh+3 of unit j ----
        {
            const int r0 = 4 * kh;
            #pragma unroll
            for (int u = 0; u < 4; ++u) {
                const int r = r0 + u;
                const float sR  = part[PARTI(0, r, 0, j)] + part[PARTI(0, r, 1, j)];
                const float sZ  = part[PARTI(1, r, 0, j)] + part[PARTI(1, r, 1, j)];
                const float sXN = part[PARTI(2, r, 0, j)] + part[PARTI(2, r, 1, j)];
                const float sHN = part[PARTI(3, r, 0, j)] + part[PARTI(3, r, 1, j)];
                const float Rg = sigmoidf_(sR + bR);
                const float Zg = sigmoidf_(sZ + bZ);
                const float Ng = tanhf(sXN + bXN + Rg * (sHN + bHN));
                hcur[u] = (1.0f - Zg) * Ng + Zg * hcur[u];
            }
            *(float4*)&hs[j][r0] = make_float4(hcur[0], hcur[1], hcur[2], hcur[3]);
        }
        if (havepf) {
            xs[nxt][lk + 0][lr] = pf.x; xs[nxt][lk + 1][lr] = pf.y;
            xs[nxt][lk + 2][lr] = pf.z; xs[nxt][lk + 3][lr] = pf.w;
        }
        __syncthreads();   // B: hs/xs ready for next step; part free
    }

    // ---- cdist^2 + argmin: each thread covers protos {tid, tid+512, tid+1024, tid+1536} ----
    float d2[4][8];
    #pragma unroll
    for (int q = 0; q < 4; ++q)
        #pragma unroll
        for (int r = 0; r < 8; ++r) d2[q][r] = 0.f;
    for (int k = 0; k < HH; ++k) {
        const float4 h0 = *(const float4*)&hs[k][0];
        const float4 h1 = *(const float4*)&hs[k][4];
        const float hv[8] = {h0.x, h0.y, h0.z, h0.w, h1.x, h1.y, h1.z, h1.w};
        const float* pk = pT + (size_t)k * PP + tid;
        #pragma unroll
        for (int q = 0; q < 4; ++q) {
            const float pv = pk[q * 512];
            #pragma unroll
            for (int r = 0; r < 8; ++r) { const float d = hv[r] - pv; d2[q][r] += d * d; }
        }
    }
    float bv[8]; int bi[8];
    #pragma unroll
    for (int r = 0; r < 8; ++r) { bv[r] = d2[0][r]; bi[r] = tid; }
    #pragma unroll
    for (int q = 1; q < 4; ++q)
        #pragma unroll
        for (int r = 0; r < 8; ++r)
            if (d2[q][r] < bv[r]) { bv[r] = d2[q][r]; bi[r] = tid + q * 512; }

    // wave argmin (lowest-index tie-break), then cross-wave via LDS
    #pragma unroll
    for (int s = 1; s < 64; s <<= 1) {
        #pragma unroll
        for (int r = 0; r < 8; ++r) {
            const float ov = __shfl_xor(bv[r], s);
            const int   oi = __shfl_xor(bi[r], s);
            if (ov < bv[r] || (ov == bv[r] && oi < bi[r])) { bv[r] = ov; bi[r] = oi; }
        }
    }
    if ((tid & 63) == 0) {
        const int w = tid >> 6;
        #pragma unroll
        for (int r = 0; r < 8; ++r) { redv[w][r] = bv[r]; redi[w][r] = bi[r]; }
    }
    __syncthreads();
    if (tid < RR) {
        float v = redv[0][tid]; int idx = redi[0][tid];
        #pragma unroll
        for (int w = 1; w < 8; ++w) {
            const float ov = redv[w][tid]; const int oi = redi[w][tid];
            if (ov < v || (ov == v && oi < idx)) { v = ov; idx = oi; }
        }
        out[row0 + tid] = idx;
    }
}

extern "C" void kernel_launch(void* const* d_in, const int* in_sizes, int n_in,
                              void* d_out, int out_size, void* d_ws, size_t ws_size,
                              hipStream_t stream) {
    const float* x      = (const float*)d_in[0];
    const float* w_ih   = (const float*)d_in[1];
    const float* w_hh   = (const float*)d_in[2];
    const float* b_ih   = (const float*)d_in[3];
    const float* b_hh   = (const float*)d_in[4];
    const float* protos = (const float*)d_in[5];
    int* out = (int*)d_out;

    float* ws   = (float*)d_ws;
    float* wIH2 = ws;                              // 98304 floats
    float* wHH2 = ws + DD * 768;                   // 196608 floats
    float* pT   = ws + DD * 768 + HH * 768;        // 524288 floats

    hipLaunchKernelGGL(prep_kernel, dim3((HH * PP + 255) / 256), dim3(256), 0, stream,
                       w_ih, w_hh, protos, wIH2, wHH2, pT);
    hipLaunchKernelGGL(gru_kernel, dim3(BATCH / RR), dim3(NTH), 0, stream,
                       x, wIH2, wHH2, b_ih, b_hh, pT, out);
}

// Round 4
// 5945.808 us; speedup vs baseline: 6.8093x; 6.8093x over previous
//
#include <hip/hip_runtime.h>

// Problem constants (fixed by the reference)
#define BATCH 2048
#define TT    256
#define DD    128
#define HH    256
#define PP    2048
#define RR    8     // batch rows per block (2048 rows / 256 CUs)
#define NTH   512   // 8 waves/block, 1 block/CU -> 2 waves/SIMD

__device__ __forceinline__ float sigmoidf_(float v) { return 1.0f / (1.0f + expf(-v)); }

// Weight layout, 4-k packed so each lane loads one coalesced float4 of 4 k's:
//   wIH4[(((k>>2)*3 + g)<<10) | (j<<2) | (k&3)] = w_ih[g*256+j][k]   (k<128)
//   wHH4[(((k>>2)*3 + g)<<10) | (j<<2) | (k&3)] = w_hh[g*256+j][k]   (k<256)
//   pT[k*2048 + p] = protos[p][k]
__global__ void prep_kernel(const float* __restrict__ w_ih, const float* __restrict__ w_hh,
                            const float* __restrict__ protos,
                            float* __restrict__ wIH4, float* __restrict__ wHH4,
                            float* __restrict__ pT) {
    int f = blockIdx.x * blockDim.x + threadIdx.x;
    if (f < DD * 768) {
        int lo = f & 3, j = (f >> 2) & 255, u = f >> 10, g = u % 3, kq = u / 3;
        wIH4[f] = w_ih[(g * 256 + j) * DD + kq * 4 + lo];
    }
    if (f < HH * 768) {
        int lo = f & 3, j = (f >> 2) & 255, u = f >> 10, g = u % 3, kq = u / 3;
        wHH4[f] = w_hh[(g * 256 + j) * HH + kq * 4 + lo];
    }
    if (f < HH * PP) {
        pT[f] = protos[(f & 2047) * HH + (f >> 11)];
    }
}

// part[s][r][kh][j]: s in {r,z,xn,hn}, r row, kh k-half, j unit (consecutive-j: conflict-free)
#define PARTI(s, r, h, j) ((((s) * 8 + (r)) * 2 + (h)) * 256 + (j))

__launch_bounds__(NTH, 2)
__global__ void gru_kernel(const float* __restrict__ x,
                           const float* __restrict__ wIH4, const float* __restrict__ wHH4,
                           const float* __restrict__ b_ih, const float* __restrict__ b_hh,
                           const float* __restrict__ pT,
                           int* __restrict__ out) {
    __shared__ float xs[2][DD][RR];          // 8 KB  x_t staging (k-major), double-buffered
    __shared__ float hs[HH][RR];             // 8 KB  hidden state (k-major)
    __shared__ float part[4 * 8 * 2 * 256];  // 64 KB partial sums
    __shared__ float redv[8][RR];
    __shared__ int   redi[8][RR];

    const int tid  = threadIdx.x;
    const int j    = tid & 255;   // hidden unit
    const int kh   = tid >> 8;    // k-half (0/1)
    const int row0 = blockIdx.x * RR;

    const float bR  = b_ih[j] + b_hh[j];
    const float bZ  = b_ih[HH + j] + b_hh[HH + j];
    const float bXN = b_ih[2 * HH + j];
    const float bHN = b_hh[2 * HH + j];

    float hcur[4] = {0.f, 0.f, 0.f, 0.f};   // rows 4*kh..4*kh+3 of unit j
    *(float4*)&hs[j][4 * kh] = make_float4(0.f, 0.f, 0.f, 0.f);

    // x loader mapping (first 4 waves): row lr, 4 cols at lk
    const int lr = tid >> 5;
    const int lk = (tid & 31) * 4;
    const float* xrow = x + (size_t)(row0 + lr) * TT * DD + lk;
    if (tid < 256) {
        float4 v = *(const float4*)(xrow);
        xs[0][lk + 0][lr] = v.x; xs[0][lk + 1][lr] = v.y;
        xs[0][lk + 2][lr] = v.z; xs[0][lk + 3][lr] = v.w;
    }
    __syncthreads();

    // per-thread stream bases: ih covers absolute k in [64*kh, 64*kh+64) -> 16 kq blocks,
    // hh covers [128*kh, 128*kh+128) -> 32 kq blocks
    const float* ihq = wIH4 + (size_t)kh * 16 * 3072 + 4 * j;
    const float* hhq = wHH4 + (size_t)kh * 32 * 3072 + 4 * j;
    const float* hb  = &hs[128 * kh][0];

    for (int t = 0; t < TT; ++t) {
        const int cur = t & 1, nxt = cur ^ 1;
        const float* xb = &xs[cur][64 * kh][0];

        float4 pf;
        const bool havepf = (t + 1 < TT) && (tid < 256);
        if (havepf) pf = *(const float4*)(xrow + (size_t)(t + 1) * DD);

        float pr[8], pz[8], pxn[8], phn[8];
        #pragma unroll
        for (int r = 0; r < 8; ++r) { pr[r] = 0.f; pz[r] = 0.f; pxn[r] = 0.f; phn[r] = 0.f; }

        // ---- input projection: 16 kq blocks (64 k) per thread ----
        #pragma unroll 4
        for (int kq = 0; kq < 16; ++kq) {
            const float4 wr4 = *(const float4*)&ihq[(size_t)(kq * 3 + 0) << 10];
            const float4 wz4 = *(const float4*)&ihq[(size_t)(kq * 3 + 1) << 10];
            const float4 wn4 = *(const float4*)&ihq[(size_t)(kq * 3 + 2) << 10];
            #pragma unroll
            for (int u = 0; u < 4; ++u) {
                const float w_r = ((const float*)&wr4)[u];
                const float w_z = ((const float*)&wz4)[u];
                const float w_n = ((const float*)&wn4)[u];
                const float4 v0 = *(const float4*)(xb + (kq * 4 + u) * 8);
                const float4 v1 = *(const float4*)(xb + (kq * 4 + u) * 8 + 4);
                const float vv[8] = {v0.x, v0.y, v0.z, v0.w, v1.x, v1.y, v1.z, v1.w};
                #pragma unroll
                for (int r = 0; r < 8; ++r) {
                    pr[r] += vv[r] * w_r; pz[r] += vv[r] * w_z; pxn[r] += vv[r] * w_n;
                }
            }
        }
        // ---- hidden projection: 32 kq blocks (128 k) per thread ----
        #pragma unroll 4
        for (int kq = 0; kq < 32; ++kq) {
            const float4 wr4 = *(const float4*)&hhq[(size_t)(kq * 3 + 0) << 10];
            const float4 wz4 = *(const float4*)&hhq[(size_t)(kq * 3 + 1) << 10];
            const float4 wn4 = *(const float4*)&hhq[(size_t)(kq * 3 + 2) << 10];
            #pragma unroll
            for (int u = 0; u < 4; ++u) {
                const float w_r = ((const float*)&wr4)[u];
                const float w_z = ((const float*)&wz4)[u];
                const float w_n = ((const float*)&wn4)[u];
                const float4 v0 = *(const float4*)(hb + (kq * 4 + u) * 8);
                const float4 v1 = *(const float4*)(hb + (kq * 4 + u) * 8 + 4);
                const float vv[8] = {v0.x, v0.y, v0.z, v0.w, v1.x, v1.y, v1.z, v1.w};
                #pragma unroll
                for (int r = 0; r < 8; ++r) {
                    pr[r] += vv[r] * w_r; pz[r] += vv[r] * w_z; phn[r] += vv[r] * w_n;
                }
            }
        }

        // ---- publish partials ----
        #pragma unroll
        for (int r = 0; r < 8; ++r) {
            part[PARTI(0, r, kh, j)] = pr[r];
            part[PARTI(1, r, kh, j)] = pz[r];
            part[PARTI(2, r, kh, j)] = pxn[r];
            part[PARTI(3, r, kh, j)] = phn[r];
        }
        __syncthreads();   // A: partials visible; all xs/hs reads done

        // ---- gates for rows 4*kh..4*kh+3 of unit j ----
        {
            const int r0 = 4 * kh;
            #pragma unroll
            for (int u = 0; u < 4; ++u) {
                const int r = r0 + u;
                const float sR  = part[PARTI(0, r, 0, j)] + part[PARTI(0, r, 1, j)];
                const float sZ  = part[PARTI(1, r, 0, j)] + part[PARTI(1, r, 1, j)];
                const float sXN = part[PARTI(2, r, 0, j)] + part[PARTI(2, r, 1, j)];
                const float sHN = part[PARTI(3, r, 0, j)] + part[PARTI(3, r, 1, j)];
                const float Rg = sigmoidf_(sR + bR);
                const float Zg = sigmoidf_(sZ + bZ);
                const float Ng = tanhf(sXN + bXN + Rg * (sHN + bHN));
                hcur[u] = (1.0f - Zg) * Ng + Zg * hcur[u];
            }
            *(float4*)&hs[j][r0] = make_float4(hcur[0], hcur[1], hcur[2], hcur[3]);
        }
        if (havepf) {
            xs[nxt][lk + 0][lr] = pf.x; xs[nxt][lk + 1][lr] = pf.y;
            xs[nxt][lk + 2][lr] = pf.z; xs[nxt][lk + 3][lr] = pf.w;
        }
        __syncthreads();   // B: hs/xs ready for next step; part free
    }

    // ---- cdist^2 + argmin: thread covers protos {tid, tid+512, tid+1024, tid+1536} ----
    float d2[4][8];
    #pragma unroll
    for (int q = 0; q < 4; ++q)
        #pragma unroll
        for (int r = 0; r < 8; ++r) d2[q][r] = 0.f;
    for (int k = 0; k < HH; ++k) {
        const float4 h0 = *(const float4*)&hs[k][0];
        const float4 h1 = *(const float4*)&hs[k][4];
        const float hv[8] = {h0.x, h0.y, h0.z, h0.w, h1.x, h1.y, h1.z, h1.w};
        const float* pk = pT + (size_t)k * PP + tid;
        #pragma unroll
        for (int q = 0; q < 4; ++q) {
            const float pv = pk[q * 512];
            #pragma unroll
            for (int r = 0; r < 8; ++r) { const float d = hv[r] - pv; d2[q][r] += d * d; }
        }
    }
    float bv[8]; int bi[8];
    #pragma unroll
    for (int r = 0; r < 8; ++r) { bv[r] = d2[0][r]; bi[r] = tid; }
    #pragma unroll
    for (int q = 1; q < 4; ++q)
        #pragma unroll
        for (int r = 0; r < 8; ++r)
            if (d2[q][r] < bv[r]) { bv[r] = d2[q][r]; bi[r] = tid + q * 512; }

    // wave argmin (lowest-index tie-break), then cross-wave via LDS
    #pragma unroll
    for (int s = 1; s < 64; s <<= 1) {
        #pragma unroll
        for (int r = 0; r < 8; ++r) {
            const float ov = __shfl_xor(bv[r], s);
            const int   oi = __shfl_xor(bi[r], s);
            if (ov < bv[r] || (ov == bv[r] && oi < bi[r])) { bv[r] = ov; bi[r] = oi; }
        }
    }
    if ((tid & 63) == 0) {
        const int w = tid >> 6;
        #pragma unroll
        for (int r = 0; r < 8; ++r) { redv[w][r] = bv[r]; redi[w][r] = bi[r]; }
    }
    __syncthreads();
    if (tid < RR) {
        float v = redv[0][tid]; int idx = redi[0][tid];
        #pragma unroll
        for (int w = 1; w < 8; ++w) {
            const float ov = redv[w][tid]; const int oi = redi[w][tid];
            if (ov < v || (ov == v && oi < idx)) { v = ov; idx = oi; }
        }
        out[row0 + tid] = idx;
    }
}

extern "C" void kernel_launch(void* const* d_in, const int* in_sizes, int n_in,
                              void* d_out, int out_size, void* d_ws, size_t ws_size,
                              hipStream_t stream) {
    const float* x      = (const float*)d_in[0];
    const float* w_ih   = (const float*)d_in[1];
    const float* w_hh   = (const float*)d_in[2];
    const float* b_ih   = (const float*)d_in[3];
    const float* b_hh   = (const float*)d_in[4];
    const float* protos = (const float*)d_in[5];
    int* out = (int*)d_out;

    float* ws   = (float*)d_ws;
    float* wIH4 = ws;                              // 98304 floats
    float* wHH4 = ws + DD * 768;                   // 196608 floats
    float* pT   = ws + DD * 768 + HH * 768;        // 524288 floats

    hipLaunchKernelGGL(prep_kernel, dim3((HH * PP + 255) / 256), dim3(256), 0, stream,
                       w_ih, w_hh, protos, wIH4, wHH4, pT);
    hipLaunchKernelGGL(gru_kernel, dim3(BATCH / RR), dim3(NTH), 0, stream,
                       x, wIH4, wHH4, b_ih, b_hh, pT, out);
}

// Round 5
// 5564.490 us; speedup vs baseline: 7.2759x; 1.0685x over previous
//
#include <hip/hip_runtime.h>

// Problem constants (fixed by the reference)
#define BATCH 2048
#define TT    256
#define DD    128
#define HH    256
#define PP    2048
#define RR    8     // batch rows per block (2048 rows / 256 CUs)
#define NTH   768   // 12 waves/block, 1 block/CU -> 3 waves/SIMD

__device__ __forceinline__ float sigmoidf_(float v) { return 1.0f / (1.0f + expf(-v)); }

// Weight layout, 4-k packed so each lane loads one coalesced float4 of 4 k's:
//   wIH4[(((k>>2)*3 + g)<<10) | (j<<2) | (k&3)] = w_ih[g*256+j][k]   (k<128)
//   wHH4[(((k>>2)*3 + g)<<10) | (j<<2) | (k&3)] = w_hh[g*256+j][k]   (k<256)
//   pT[k*2048 + p] = protos[p][k]
__global__ void prep_kernel(const float* __restrict__ w_ih, const float* __restrict__ w_hh,
                            const float* __restrict__ protos,
                            float* __restrict__ wIH4, float* __restrict__ wHH4,
                            float* __restrict__ pT) {
    int f = blockIdx.x * blockDim.x + threadIdx.x;
    if (f < DD * 768) {
        int lo = f & 3, j = (f >> 2) & 255, u = f >> 10, g = u % 3, kq = u / 3;
        wIH4[f] = w_ih[(g * 256 + j) * DD + kq * 4 + lo];
    }
    if (f < HH * 768) {
        int lo = f & 3, j = (f >> 2) & 255, u = f >> 10, g = u % 3, kq = u / 3;
        wHH4[f] = w_hh[(g * 256 + j) * HH + kq * 4 + lo];
    }
    if (f < HH * PP) {
        pT[f] = protos[(f & 2047) * HH + (f >> 11)];
    }
}

// FMA one k (8 rows, 3 streams) from a 32B activation row (broadcast LDS read)
#define FMA4(WR, WZ, WN, A) do {                                        \
    const float4 a0 = *(const float4*)(A);                              \
    const float4 a1 = *(const float4*)((A) + 4);                        \
    pr[0] += a0.x*(WR); pz[0] += a0.x*(WZ); pn[0] += a0.x*(WN);         \
    pr[1] += a0.y*(WR); pz[1] += a0.y*(WZ); pn[1] += a0.y*(WN);         \
    pr[2] += a0.z*(WR); pz[2] += a0.z*(WZ); pn[2] += a0.z*(WN);         \
    pr[3] += a0.w*(WR); pz[3] += a0.w*(WZ); pn[3] += a0.w*(WN);         \
    pr[4] += a1.x*(WR); pz[4] += a1.x*(WZ); pn[4] += a1.x*(WN);         \
    pr[5] += a1.y*(WR); pz[5] += a1.y*(WZ); pn[5] += a1.y*(WN);         \
    pr[6] += a1.z*(WR); pz[6] += a1.z*(WZ); pn[6] += a1.z*(WN);         \
    pr[7] += a1.w*(WR); pz[7] += a1.w*(WZ); pn[7] += a1.w*(WN);         \
} while (0)

__launch_bounds__(NTH, 3)
__global__ void gru_kernel(const float* __restrict__ x,
                           const float* __restrict__ wIH4, const float* __restrict__ wHH4,
                           const float* __restrict__ b_ih, const float* __restrict__ b_hh,
                           const float* __restrict__ pT,
                           int* __restrict__ out) {
    __shared__ float xs[2][DD][RR];        // 8 KB  x_t staging (k-major), double-buffered
    __shared__ float hs[HH][RR];           // 8 KB  hidden state (k-major)
    __shared__ float pa_buf[8 * 3 * 256];  // 24 KB r-gate partials [row][kt][j]
    __shared__ float pz_buf[8 * 3 * 256];  // 24 KB z-gate partials
    __shared__ float px_buf[8 * 256];      //  8 KB xn partials (kt=0) [row][j]
    __shared__ float ph_buf[8 * 2 * 256];  // 16 KB hn partials (kt=1,2) [row][kt-1][j]
    __shared__ float redv[12][RR];
    __shared__ int   redi[12][RR];

    const int tid  = threadIdx.x;
    const int j    = tid & 255;   // hidden unit
    const int kt   = tid >> 8;    // k-third: 0 = ih[0:128), 1 = hh[0:128), 2 = hh[128:256)
    const int row0 = blockIdx.x * RR;

    const float bR  = b_ih[j] + b_hh[j];
    const float bZ  = b_ih[HH + j] + b_hh[HH + j];
    const float bXN = b_ih[2 * HH + j];
    const float bHN = b_hh[2 * HH + j];

    float hcur[4] = {0.f, 0.f, 0.f, 0.f};   // kt<2: rows 4*kt..4*kt+3 of unit j
    if (kt < 2) *(float4*)&hs[j][4 * kt] = make_float4(0.f, 0.f, 0.f, 0.f);

    // x loader mapping (first 4 waves): row lr, 4 cols at lk
    const int lr = tid >> 5;
    const int lk = (tid & 31) * 4;
    const float* xrow = x + (size_t)(row0 + lr) * TT * DD + lk;
    if (tid < 256) {
        float4 v = *(const float4*)(xrow);
        xs[0][lk + 0][lr] = v.x; xs[0][lk + 1][lr] = v.y;
        xs[0][lk + 2][lr] = v.z; xs[0][lk + 3][lr] = v.w;
    }
    __syncthreads();

    // per-thread weight stream base (32 kq-blocks of 4 k each; each weight read once/block/step)
    const float* wbase = (kt == 0) ? (wIH4 + 4 * j)
                                   : (wHH4 + (size_t)(kt - 1) * 32 * 3072 + 4 * j);
    const float* hbase = &hs[(kt == 0 ? 0 : (kt - 1) * 128)][0];  // kt>0 activation base

    for (int t = 0; t < TT; ++t) {
        const int cur = t & 1, nxt = cur ^ 1;
        const float* abase = (kt == 0) ? &xs[cur][0][0] : hbase;

        float4 pf;
        const bool havepf = (t + 1 < TT) && (tid < 256);
        if (havepf) pf = *(const float4*)(xrow + (size_t)(t + 1) * DD);

        float pr[8], pz[8], pn[8];
        #pragma unroll
        for (int r = 0; r < 8; ++r) { pr[r] = 0.f; pz[r] = 0.f; pn[r] = 0.f; }

        // ---- 32 kq blocks (128 k) per thread, 3 gate-streams, 8 rows ----
        #pragma unroll 2
        for (int kq = 0; kq < 32; ++kq) {
            const float4 w0 = *(const float4*)&wbase[(size_t)(kq * 3 + 0) << 10];
            const float4 w1 = *(const float4*)&wbase[(size_t)(kq * 3 + 1) << 10];
            const float4 w2 = *(const float4*)&wbase[(size_t)(kq * 3 + 2) << 10];
            const float* ak = abase + kq * 32;
            FMA4(w0.x, w1.x, w2.x, ak);
            FMA4(w0.y, w1.y, w2.y, ak + 8);
            FMA4(w0.z, w1.z, w2.z, ak + 16);
            FMA4(w0.w, w1.w, w2.w, ak + 24);
        }

        // ---- publish partials (consecutive-j: conflict-free) ----
        #pragma unroll
        for (int r = 0; r < 8; ++r) {
            pa_buf[(r * 3 + kt) * 256 + j] = pr[r];
            pz_buf[(r * 3 + kt) * 256 + j] = pz[r];
        }
        if (kt == 0) {
            #pragma unroll
            for (int r = 0; r < 8; ++r) px_buf[r * 256 + j] = pn[r];
        } else {
            #pragma unroll
            for (int r = 0; r < 8; ++r) ph_buf[(r * 2 + (kt - 1)) * 256 + j] = pn[r];
        }
        __syncthreads();   // A: partials visible; all xs/hs reads done

        // ---- gates: kt=0 -> rows 0-3, kt=1 -> rows 4-7, kt=2 idle ----
        if (kt < 2) {
            #pragma unroll
            for (int u = 0; u < 4; ++u) {
                const int r = 4 * kt + u;
                const float sR = pa_buf[(r * 3 + 0) * 256 + j] + pa_buf[(r * 3 + 1) * 256 + j]
                               + pa_buf[(r * 3 + 2) * 256 + j] + bR;
                const float sZ = pz_buf[(r * 3 + 0) * 256 + j] + pz_buf[(r * 3 + 1) * 256 + j]
                               + pz_buf[(r * 3 + 2) * 256 + j] + bZ;
                const float sXN = px_buf[r * 256 + j] + bXN;
                const float sHN = ph_buf[(r * 2 + 0) * 256 + j] + ph_buf[(r * 2 + 1) * 256 + j] + bHN;
                const float Rg = sigmoidf_(sR);
                const float Zg = sigmoidf_(sZ);
                const float Ng = tanhf(sXN + Rg * sHN);
                hcur[u] = (1.0f - Zg) * Ng + Zg * hcur[u];
            }
            *(float4*)&hs[j][4 * kt] = make_float4(hcur[0], hcur[1], hcur[2], hcur[3]);
        }
        if (havepf) {
            xs[nxt][lk + 0][lr] = pf.x; xs[nxt][lk + 1][lr] = pf.y;
            xs[nxt][lk + 2][lr] = pf.z; xs[nxt][lk + 3][lr] = pf.w;
        }
        __syncthreads();   // B: hs/xs ready for next step; part buffers free
    }

    // ---- cdist^2 + argmin: thread covers protos {tid, tid+768, tid+1536} ----
    float bv[8]; int bi[8];
    #pragma unroll
    for (int r = 0; r < 8; ++r) { bv[r] = 3.4e38f; bi[r] = 0; }
    for (int m = 0; m < 3; ++m) {
        const int p = tid + m * 768;
        if (p < PP) {
            float d2[8];
            #pragma unroll
            for (int r = 0; r < 8; ++r) d2[r] = 0.f;
            for (int k = 0; k < HH; ++k) {
                const float pv = pT[(size_t)k * PP + p];
                const float4 h0 = *(const float4*)&hs[k][0];
                const float4 h1 = *(const float4*)&hs[k][4];
                float d;
                d = h0.x - pv; d2[0] += d * d;
                d = h0.y - pv; d2[1] += d * d;
                d = h0.z - pv; d2[2] += d * d;
                d = h0.w - pv; d2[3] += d * d;
                d = h1.x - pv; d2[4] += d * d;
                d = h1.y - pv; d2[5] += d * d;
                d = h1.z - pv; d2[6] += d * d;
                d = h1.w - pv; d2[7] += d * d;
            }
            #pragma unroll
            for (int r = 0; r < 8; ++r)
                if (d2[r] < bv[r]) { bv[r] = d2[r]; bi[r] = p; }  // ascending p: ties keep lowest
        }
    }
    // wave argmin (lowest-index tie-break), then cross-wave via LDS
    #pragma unroll
    for (int s = 1; s < 64; s <<= 1) {
        #pragma unroll
        for (int r = 0; r < 8; ++r) {
            const float ov = __shfl_xor(bv[r], s);
            const int   oi = __shfl_xor(bi[r], s);
            if (ov < bv[r] || (ov == bv[r] && oi < bi[r])) { bv[r] = ov; bi[r] = oi; }
        }
    }
    if ((tid & 63) == 0) {
        const int w = tid >> 6;
        #pragma unroll
        for (int r = 0; r < 8; ++r) { redv[w][r] = bv[r]; redi[w][r] = bi[r]; }
    }
    __syncthreads();
    if (tid < RR) {
        float v = redv[0][tid]; int idx = redi[0][tid];
        #pragma unroll
        for (int w = 1; w < 12; ++w) {
            const float ov = redv[w][tid]; const int oi = redi[w][tid];
            if (ov < v || (ov == v && oi < idx)) { v = ov; idx = oi; }
        }
        out[row0 + tid] = idx;
    }
}

extern "C" void kernel_launch(void* const* d_in, const int* in_sizes, int n_in,
                              void* d_out, int out_size, void* d_ws, size_t ws_size,
                              hipStream_t stream) {
    const float* x      = (const float*)d_in[0];
    const float* w_ih   = (const float*)d_in[1];
    const float* w_hh   = (const float*)d_in[2];
    const float* b_ih   = (const float*)d_in[3];
    const float* b_hh   = (const float*)d_in[4];
    const float* protos = (const float*)d_in[5];
    int* out = (int*)d_out;

    float* ws   = (float*)d_ws;
    float* wIH4 = ws;                              // 98304 floats
    float* wHH4 = ws + DD * 768;                   // 196608 floats
    float* pT   = ws + DD * 768 + HH * 768;        // 524288 floats

    hipLaunchKernelGGL(prep_kernel, dim3((HH * PP + 255) / 256), dim3(256), 0, stream,
                       w_ih, w_hh, protos, wIH4, wHH4, pT);
    hipLaunchKernelGGL(gru_kernel, dim3(BATCH / RR), dim3(NTH), 0, stream,
                       x, wIH4, wHH4, b_ih, b_hh, pT, out);
}